// Round 2
// baseline (403.508 us; speedup 1.0000x reference)
//
#include <hip/hip_runtime.h>
#include <stdint.h>
#include <math.h>

// Problem geometry (fixed by the reference):
//   x: (32, 256, 56, 56) fp32   W: (256, 256, 3, 3) fp32
//   y = conv(sign(x), sign(W), pad=1) -> BN(batch stats, training) -> Hardtanh
#define N_IMG 32
#define C_IN  256
#define HW    56
#define P_PIX (HW*HW)          // 3136 pixels per image
#define P4    (P_PIX/4)        // 784 float4 per (n,o) row
#define OC    256
#define WPC   8                // 32-bit words per pixel (256 ch / 32)
#define NPIX  (N_IMG*P_PIX)    // 100352
#define NTOT  ((double)N_IMG*(double)P_PIX)
#define WSTRIDE 80             // dwords per output channel in packed W (72 used, pad 80)

// ---------------------------------------------------------------------------
// 1) Bit-pack activations: px[pixel][word]; bit k of word w = (x[n][32w+k][p] >= 0)
__global__ __launch_bounds__(256) void pack_x_kernel(const float* __restrict__ x,
                                                     uint32_t* __restrict__ px) {
    int idx  = blockIdx.x * 256 + threadIdx.x;   // 0 .. 8*NPIX-1
    int word = idx / NPIX;
    int r    = idx - word * NPIX;
    int n    = r / P_PIX;
    int p    = r - n * P_PIX;
    const float* xp = x + ((size_t)(n * C_IN + word * 32)) * P_PIX + p;
    uint32_t bits = 0;
#pragma unroll
    for (int k = 0; k < 32; ++k) {
        float v = xp[(size_t)k * P_PIX];
        bits |= (v >= 0.0f) ? (1u << k) : 0u;
    }
    px[((size_t)(n * P_PIX + p)) * WPC + word] = bits;
}

// ---------------------------------------------------------------------------
// 2) Bit-pack weights + per-(o, border-config) correction table; zero stat accums.
//    For a border pixel, invalid taps are computed with x-word = 0, which
//    spuriously contributes (256 - 2*popc(w_tap)); corr removes exactly that.
__global__ void pack_w_kernel(const float* __restrict__ Wt,
                              uint32_t* __restrict__ wp,
                              int* __restrict__ corr,
                              long long* __restrict__ sums,
                              long long* __restrict__ sumsq) {
    __shared__ int lpop[72];
    __shared__ int ltap[9];
    int o = blockIdx.x;
    int t = threadIdx.x;     // 128 threads
    if (t == 0) { sums[o] = 0; sumsq[o] = 0; }   // re-zero every launch (ws poisoned)
    if (t < 72) {
        int tap = t >> 3;
        int word = t & 7;
        const float* wpr = Wt + ((size_t)(o * C_IN + word * 32)) * 9 + tap;
        uint32_t bits = 0;
#pragma unroll
        for (int k = 0; k < 32; ++k) {
            float v = wpr[(size_t)k * 9];
            bits |= (v >= 0.0f) ? (1u << k) : 0u;
        }
        wp[o * WSTRIDE + t] = bits;
        lpop[t] = __popc(bits);
    }
    __syncthreads();
    if (t < 9) {
        int s = 0;
#pragma unroll
        for (int w = 0; w < 8; ++w) s += lpop[t * 8 + w];
        ltap[t] = s;
    }
    __syncthreads();
    if (t < 9) {
        int vc = t / 3, hc = t % 3;   // 0=interior, 1=low edge, 2=high edge
        int c = 0;
        for (int dy = -1; dy <= 1; ++dy)
            for (int dx = -1; dx <= 1; ++dx) {
                bool inv = (dy == -1 && vc == 1) || (dy == 1 && vc == 2) ||
                           (dx == -1 && hc == 1) || (dx == 1 && hc == 2);
                if (inv) {
                    int tap = (dy + 1) * 3 + (dx + 1);
                    c += 256 - 2 * ltap[tap];
                }
            }
        corr[o * 9 + t] = c;
    }
}

// ---------------------------------------------------------------------------
// 3) Binary conv via xor+popcount, with fused per-channel stats.
//    Thread owns one pixel (9x8 packed words in VGPRs), loops 64 out-channels.
//    Weight reads are wave-uniform -> scalar loads. Stats: wave butterfly ->
//    LDS int -> one int64 global atomic per (block, channel). Exact/deterministic:
//    per-block |sum| <= 128*2304, sumsq <= 128*2304^2 = 680M < 2^31.
template <typename YT>
__global__ __launch_bounds__(128) void bconv_kernel(const uint32_t* __restrict__ px,
                                                    const uint32_t* __restrict__ wp,
                                                    const int* __restrict__ corr,
                                                    YT* __restrict__ yout,
                                                    long long* __restrict__ sums,
                                                    long long* __restrict__ sumsq) {
    __shared__ int ls[64];
    __shared__ int lq[64];
    int blk  = blockIdx.x;
    int pc   = blk >> 2;          // pixel-chunk 0..783
    int osec = blk & 3;           // o-section 0..3 (64 channels each)
    int gi   = pc * 128 + threadIdx.x;   // 0..NPIX-1
    int n = gi / P_PIX;
    int p = gi - n * P_PIX;
    int h = p / HW;
    int w = p - h * HW;

    if (threadIdx.x < 64) { ls[threadIdx.x] = 0; lq[threadIdx.x] = 0; }

    uint32_t xr[72];
#pragma unroll
    for (int i = 0; i < 9; ++i) {
        int dy = i / 3 - 1, dx = i % 3 - 1;
        int hh = h + dy, ww = w + dx;
        bool valid = (hh >= 0) && (hh < HW) && (ww >= 0) && (ww < HW);
        const uint4* src = (const uint4*)(px + ((size_t)(n * P_PIX + hh * HW + ww)) * WPC);
        uint4 a = valid ? src[0] : make_uint4(0u, 0u, 0u, 0u);
        uint4 b = valid ? src[1] : make_uint4(0u, 0u, 0u, 0u);
        xr[i * 8 + 0] = a.x; xr[i * 8 + 1] = a.y; xr[i * 8 + 2] = a.z; xr[i * 8 + 3] = a.w;
        xr[i * 8 + 4] = b.x; xr[i * 8 + 5] = b.y; xr[i * 8 + 6] = b.z; xr[i * 8 + 7] = b.w;
    }

    int vc = (h == 0) ? 1 : ((h == HW - 1) ? 2 : 0);
    int hc = (w == 0) ? 1 : ((w == HW - 1) ? 2 : 0);
    const int* cptr = corr + vc * 3 + hc;
    __syncthreads();   // ls/lq zeroed

    int o0 = osec * 64;
    YT* yp = yout + ((size_t)(n * OC + o0)) * P_PIX + p;
    for (int oo = 0; oo < 64; ++oo) {
        int o = o0 + oo;
        const uint4* wq = (const uint4*)(wp + o * WSTRIDE);
        int acc = 0;
#pragma unroll
        for (int j = 0; j < 18; ++j) {
            uint4 wv = wq[j];
            acc += __popc(xr[4 * j + 0] ^ wv.x);
            acc += __popc(xr[4 * j + 1] ^ wv.y);
            acc += __popc(xr[4 * j + 2] ^ wv.z);
            acc += __popc(xr[4 * j + 3] ^ wv.w);
        }
        int v = 2304 - 2 * acc - cptr[o * 9];
        *yp = (YT)v;
        yp += P_PIX;
        int s = v, q = v * v;
#pragma unroll
        for (int off = 32; off > 0; off >>= 1) {
            s += __shfl_xor(s, off, 64);
            q += __shfl_xor(q, off, 64);
        }
        if ((threadIdx.x & 63) == 0) {
            atomicAdd(&ls[oo], s);
            atomicAdd(&lq[oo], q);
        }
    }
    __syncthreads();
    if (threadIdx.x < 64) {
        atomicAdd((unsigned long long*)&sums[o0 + threadIdx.x],
                  (unsigned long long)(long long)ls[threadIdx.x]);
        atomicAdd((unsigned long long*)&sumsq[o0 + threadIdx.x],
                  (unsigned long long)(long long)lq[threadIdx.x]);
    }
}

// ---------------------------------------------------------------------------
// 4) Fused scale/bias derivation + BN affine + Hardtanh. One block per channel.
template <typename YT>
__global__ __launch_bounds__(256) void apply_kernel(const YT* __restrict__ y,
                                                    float* __restrict__ out,
                                                    const long long* __restrict__ sums,
                                                    const long long* __restrict__ sumsq,
                                                    const float* __restrict__ gamma,
                                                    const float* __restrict__ beta) {
    int o = blockIdx.x;
    double invN = 1.0 / NTOT;
    double mean = (double)sums[o] * invN;
    double var  = (double)sumsq[o] * invN - mean * mean;
    double sc   = (double)gamma[o] / sqrt(var + 1e-5);
    float s = (float)sc;
    float b = (float)((double)beta[o] - mean * sc);
    for (int idx = threadIdx.x; idx < N_IMG * P4; idx += 256) {
        int n  = idx / P4;
        int p4 = idx - n * P4;
        size_t base = ((size_t)(n * OC + o)) * P_PIX + 4 * p4;
        float4 v;
        const YT* src = y + base;
        v.x = (float)src[0]; v.y = (float)src[1]; v.z = (float)src[2]; v.w = (float)src[3];
        v.x = fminf(fmaxf(fmaf(v.x, s, b), -1.0f), 1.0f);
        v.y = fminf(fmaxf(fmaf(v.y, s, b), -1.0f), 1.0f);
        v.z = fminf(fmaxf(fmaf(v.z, s, b), -1.0f), 1.0f);
        v.w = fminf(fmaxf(fmaf(v.w, s, b), -1.0f), 1.0f);
        *(float4*)(out + base) = v;
    }
}

// ---------------------------------------------------------------------------
extern "C" void kernel_launch(void* const* d_in, const int* in_sizes, int n_in,
                              void* d_out, int out_size, void* d_ws, size_t ws_size,
                              hipStream_t stream) {
    const float* x     = (const float*)d_in[0];
    const float* Wt    = (const float*)d_in[1];
    const float* gamma = (const float*)d_in[2];
    const float* beta  = (const float*)d_in[3];
    float* out = (float*)d_out;
    char* ws = (char*)d_ws;

    // Workspace layout (base: ~3.3 MB; optional int16 y-stage: +51.4 MB)
    uint32_t*  px    = (uint32_t*) (ws);             // 32*3136*8*4 = 3,211,264 B
    uint32_t*  wp    = (uint32_t*) (ws + 3211264);   // 256*80*4    =    81,920 B
    int*       corr  = (int*)      (ws + 3293184);   // 256*9*4     =     9,216 B
    long long* sums  = (long long*)(ws + 3302400);   // 256*8       =     2,048 B
    long long* sumsq = (long long*)(ws + 3304448);   // 256*8       =     2,048 B
    short*     y16   = (short*)    (ws + 3306496);   // 25,690,112*2 = 51,380,224 B
    const size_t WS_NEED_I16 = 3306496ull + 51380224ull;   // 54,686,720 B

    hipLaunchKernelGGL(pack_x_kernel, dim3(8 * NPIX / 256), dim3(256), 0, stream, x, px);
    hipLaunchKernelGGL(pack_w_kernel, dim3(OC), dim3(128), 0, stream, Wt, wp, corr, sums, sumsq);
    if (ws_size >= WS_NEED_I16) {
        // stage y as int16 in workspace (halves stage write + reload read)
        hipLaunchKernelGGL(bconv_kernel<short>, dim3((NPIX / 128) * 4), dim3(128), 0, stream,
                           px, wp, corr, y16, sums, sumsq);
        hipLaunchKernelGGL(apply_kernel<short>, dim3(OC), dim3(256), 0, stream,
                           y16, out, sums, sumsq, gamma, beta);
    } else {
        // fallback: stage y as float in d_out, apply in place
        hipLaunchKernelGGL(bconv_kernel<float>, dim3((NPIX / 128) * 4), dim3(128), 0, stream,
                           px, wp, corr, out, sums, sumsq);
        hipLaunchKernelGGL(apply_kernel<float>, dim3(OC), dim3(256), 0, stream,
                           out, out, sums, sumsq, gamma, beta);
    }
}